// Round 3
// baseline (580.123 us; speedup 1.0000x reference)
//
#include <hip/hip_runtime.h>
#include <math.h>

// GCN 5-layer: per layer relu(A @ (h @ W) + b), A = sym-normalized adj w/ self-loops.
// CSR-by-dst build (no float atomics), aggregate on the narrow side of each GEMM,
// fold dinv[src] row-scaling into GEMM epilogues. All fp32.
// R2: hierarchical scan (was 160us single-block).
// R3: binned 2-pass CSR fill — old k_fill had 107MB WRITE_SIZE (16x write
//     amplification from random 4B stores); bucket=32 dsts makes both passes
//     cache-line-local, pass2 counters live in LDS.

__global__ __launch_bounds__(256) void k_count(const int* __restrict__ dst,
                                               int* __restrict__ deg, int E) {
    int e = blockIdx.x * 256 + threadIdx.x;
    if (e < E) atomicAdd(&deg[dst[e]], 1);
}

__global__ __launch_bounds__(256) void k_dinv(const int* __restrict__ deg,
                                              float* __restrict__ dinv, int n) {
    int i = blockIdx.x * 256 + threadIdx.x;
    if (i < n) dinv[i] = 1.0f / sqrtf((float)(deg[i] + 1));  // +1 self-loop
}

// ---- hierarchical exclusive scan of deg[0..n) -> offs[0..n] ----
__global__ __launch_bounds__(256) void k_scan_part(const int* __restrict__ deg,
                                                   int* __restrict__ part, int n) {
    __shared__ int red[256];
    int t = threadIdx.x;
    int base = blockIdx.x * 2048 + t * 8;
    int s = 0;
#pragma unroll
    for (int i = 0; i < 8; ++i) { int idx = base + i; if (idx < n) s += deg[idx]; }
    red[t] = s;
    __syncthreads();
    for (int d = 128; d > 0; d >>= 1) {
        if (t < d) red[t] += red[t + d];
        __syncthreads();
    }
    if (t == 0) part[blockIdx.x] = red[0];
}

__global__ __launch_bounds__(256) void k_scan_top(int* __restrict__ part, int nb,
                                                  int* __restrict__ offs, int n) {
    __shared__ int sh[256];
    int t = threadIdx.x;
    int v = (t < nb) ? part[t] : 0;
    sh[t] = v;
    __syncthreads();
    for (int d = 1; d < 256; d <<= 1) {
        int u = (t >= d) ? sh[t - d] : 0;
        __syncthreads();
        sh[t] += u;
        __syncthreads();
    }
    if (t < nb) part[t] = sh[t] - v;
    if (t == 255) offs[n] = sh[255];
}

__global__ __launch_bounds__(256) void k_scan_emit(const int* __restrict__ deg,
                                                   const int* __restrict__ part,
                                                   int* __restrict__ offs, int n) {
    __shared__ int red[256];
    int t = threadIdx.x;
    int base = blockIdx.x * 2048 + t * 8;
    int loc[8];
    int s = 0;
#pragma unroll
    for (int i = 0; i < 8; ++i) {
        int idx = base + i;
        int d = (idx < n) ? deg[idx] : 0;
        loc[i] = s; s += d;
    }
    red[t] = s;
    __syncthreads();
    for (int d = 1; d < 256; d <<= 1) {
        int u = (t >= d) ? red[t - d] : 0;
        __syncthreads();
        red[t] += u;
        __syncthreads();
    }
    int ex = red[t] - s;
    int b = part[blockIdx.x] + ex;
#pragma unroll
    for (int i = 0; i < 8; ++i) {
        int idx = base + i;
        if (idx < n) offs[idx] = b + loc[i];
    }
}
// ---- end scan ----

// ---- binned 2-pass CSR fill (bucket = 32 consecutive dst nodes) ----
// Pass 1: append (src<<5 | dst&31) into bucket region [offs[32b], offs[32b+32))
__global__ __launch_bounds__(256) void k_fill_bin(const int* __restrict__ src,
                                                  const int* __restrict__ dst,
                                                  const int* __restrict__ offs,
                                                  int* __restrict__ bcnt,
                                                  unsigned* __restrict__ tmp, int E) {
    int e = blockIdx.x * 256 + threadIdx.x;
    if (e < E) {
        int d = dst[e];
        int b = d >> 5;
        int p = offs[b << 5] + atomicAdd(&bcnt[b], 1);
        tmp[p] = ((unsigned)src[e] << 5) | (unsigned)(d & 31);
    }
}

// Pass 2: one block per bucket; per-dst counters in LDS (block owns its 32 dsts).
__global__ __launch_bounds__(256) void k_fill_csr(const unsigned* __restrict__ tmp,
                                                  const int* __restrict__ offs,
                                                  int* __restrict__ csr, int n) {
    __shared__ int lcnt[32];
    __shared__ int lbase[32];
    int b = blockIdx.x;
    int t = threadIdx.x;
    int v0 = b << 5;
    if (t < 32) {
        lcnt[t] = 0;
        int vv = v0 + t;
        lbase[t] = (vv <= n) ? offs[vv] : offs[n];
    }
    __syncthreads();
    int lo = lbase[0];
    int hi = (v0 + 32 <= n) ? offs[v0 + 32] : offs[n];
    for (int p = lo + t; p < hi; p += 256) {
        unsigned v = tmp[p];
        int d0 = (int)(v & 31u);
        int s  = (int)(v >> 5);
        int pos = lbase[d0] + atomicAdd(&lcnt[d0], 1);
        csr[pos] = s;
    }
}
// ---- end fill ----

// Layer-1 aggregation straight from x: out[v] = dinv[v]*(sum_u x[u]*dinv[u] + x[v]*dinv[v])
__global__ __launch_bounds__(256) void k_agg_l1(const float* __restrict__ X,
                                                const float* __restrict__ dinv,
                                                const int* __restrict__ offs,
                                                const int* __restrict__ csr,
                                                float* __restrict__ Y, int n) {
    constexpr int W = 64;
    int t = blockIdx.x * 256 + threadIdx.x;
    int v = t / W, c = t % W;
    if (v >= n) return;
    float dv = dinv[v];
    float sum = X[(size_t)v * W + c] * dv;
    int e = offs[v], re = offs[v + 1];
    for (; e + 4 <= re; e += 4) {
        int u0 = csr[e], u1 = csr[e + 1], u2 = csr[e + 2], u3 = csr[e + 3];
        float a0 = X[(size_t)u0 * W + c] * dinv[u0];
        float a1 = X[(size_t)u1 * W + c] * dinv[u1];
        float a2 = X[(size_t)u2 * W + c] * dinv[u2];
        float a3 = X[(size_t)u3 * W + c] * dinv[u3];
        sum += a0 + a1 + a2 + a3;
    }
    for (; e < re; ++e) { int u = csr[e]; sum += X[(size_t)u * W + c] * dinv[u]; }
    Y[(size_t)v * W + c] = dv * sum;
}

// Generic aggregation over pre-scaled rows S: out[v] = act(dinv[v]*(sum_u S[u] + S[v]) + b)
template <int W, bool RELU>
__global__ __launch_bounds__(256) void k_agg(const float* __restrict__ S,
                                             const float* __restrict__ dinv,
                                             const int* __restrict__ offs,
                                             const int* __restrict__ csr,
                                             const float* __restrict__ bg,
                                             float* __restrict__ Y, int n) {
    int t = blockIdx.x * 256 + threadIdx.x;
    int v = t / W, c = t % W;
    if (v >= n) return;
    float sum = S[(size_t)v * W + c];
    int e = offs[v], re = offs[v + 1];
    for (; e + 4 <= re; e += 4) {
        int u0 = csr[e], u1 = csr[e + 1], u2 = csr[e + 2], u3 = csr[e + 3];
        float a0 = S[(size_t)u0 * W + c];
        float a1 = S[(size_t)u1 * W + c];
        float a2 = S[(size_t)u2 * W + c];
        float a3 = S[(size_t)u3 * W + c];
        sum += a0 + a1 + a2 + a3;
    }
    for (; e < re; ++e) sum += S[(size_t)csr[e] * W + c];
    float r = dinv[v] * sum + bg[c];
    if (RELU) r = fmaxf(r, 0.0f);
    Y[(size_t)v * W + c] = r;
}

// Tall-skinny GEMM: Y[n,OUT] = X[n,IN] @ Wg[IN,OUT]
//   EPI==0: += bias, relu    EPI==1: *= dinv[row]
template <int IN, int OUT, int EPI>
__global__ __launch_bounds__(256) void k_gemm(const float* __restrict__ X,
                                              const float* __restrict__ Wg,
                                              const float* __restrict__ bg,
                                              const float* __restrict__ dinv,
                                              float* __restrict__ Y, int nrows) {
    constexpr int TPR = OUT / 4;
    constexpr int GROUPS = 256 / TPR;
    constexpr int ROWS = GROUPS * 2;
    __shared__ __align__(16) float Wl[IN * OUT];
    __shared__ __align__(16) float xl[ROWS * IN];
    __shared__ float bl[OUT];
    int tid = threadIdx.x;
    for (int i = tid; i < IN * OUT; i += 256) Wl[i] = Wg[i];
    if (EPI == 0)
        for (int i = tid; i < OUT; i += 256) bl[i] = bg[i];
    int base = blockIdx.x * ROWS;
    for (int i = tid; i < ROWS * IN; i += 256) {
        int r = base + i / IN;
        xl[i] = (r < nrows) ? X[(size_t)base * IN + i] : 0.0f;
    }
    __syncthreads();
    int g = tid / TPR;
    int c0 = (tid % TPR) * 4;
    int r0 = base + g * 2, r1 = r0 + 1;
    int l0 = (g * 2) * IN, l1 = l0 + IN;
    float4 acc0 = make_float4(0.f, 0.f, 0.f, 0.f);
    float4 acc1 = make_float4(0.f, 0.f, 0.f, 0.f);
#pragma unroll 8
    for (int k = 0; k < IN; ++k) {
        float4 w = *(const float4*)&Wl[k * OUT + c0];
        float a0 = xl[l0 + k], a1 = xl[l1 + k];
        acc0.x += a0 * w.x; acc0.y += a0 * w.y; acc0.z += a0 * w.z; acc0.w += a0 * w.w;
        acc1.x += a1 * w.x; acc1.y += a1 * w.y; acc1.z += a1 * w.z; acc1.w += a1 * w.w;
    }
    if (EPI == 0) {
        float bx = bl[c0], by = bl[c0 + 1], bz = bl[c0 + 2], bw = bl[c0 + 3];
        acc0.x = fmaxf(acc0.x + bx, 0.f); acc0.y = fmaxf(acc0.y + by, 0.f);
        acc0.z = fmaxf(acc0.z + bz, 0.f); acc0.w = fmaxf(acc0.w + bw, 0.f);
        acc1.x = fmaxf(acc1.x + bx, 0.f); acc1.y = fmaxf(acc1.y + by, 0.f);
        acc1.z = fmaxf(acc1.z + bz, 0.f); acc1.w = fmaxf(acc1.w + bw, 0.f);
    } else {
        if (r0 < nrows) { float d0 = dinv[r0]; acc0.x *= d0; acc0.y *= d0; acc0.z *= d0; acc0.w *= d0; }
        if (r1 < nrows) { float d1 = dinv[r1]; acc1.x *= d1; acc1.y *= d1; acc1.z *= d1; acc1.w *= d1; }
    }
    if (r0 < nrows) *(float4*)&Y[(size_t)r0 * OUT + c0] = acc0;
    if (r1 < nrows) *(float4*)&Y[(size_t)r1 * OUT + c0] = acc1;
}

__global__ __launch_bounds__(256) void k_gemm5(const float* __restrict__ X,
                                               const float* __restrict__ Wg,
                                               const float* __restrict__ dinv,
                                               float* __restrict__ Y, int n) {
    int r = blockIdx.x * 256 + threadIdx.x;
    if (r >= n) return;
    float acc = 0.f;
#pragma unroll
    for (int k = 0; k < 16; ++k) acc += X[(size_t)r * 16 + k] * Wg[k];
    Y[r] = acc * dinv[r];
}

extern "C" void kernel_launch(void* const* d_in, const int* in_sizes, int n_in,
                              void* d_out, int out_size, void* d_ws, size_t ws_size,
                              hipStream_t stream) {
    const float* x  = (const float*)d_in[0];
    const int*   ei = (const int*)d_in[1];
    const float* W1 = (const float*)d_in[2];  const float* b1 = (const float*)d_in[3];
    const float* W2 = (const float*)d_in[4];  const float* b2 = (const float*)d_in[5];
    const float* W3 = (const float*)d_in[6];  const float* b3 = (const float*)d_in[7];
    const float* W4 = (const float*)d_in[8];  const float* b4 = (const float*)d_in[9];
    const float* W5 = (const float*)d_in[10]; const float* b5 = (const float*)d_in[11];

    const int N = in_sizes[0] / 64;   // 100000
    const int E = in_sizes[1] / 2;    // 1600000
    const int* src = ei;
    const int* dst = ei + E;
    const int NB32 = (N + 31) / 32;   // 3125 buckets

    char* ws = (char*)d_ws;
    size_t off = 0;
    auto alloc = [&](size_t bytes) -> void* {
        void* p = ws + off;
        off = (off + bytes + 255) & ~(size_t)255;
        return p;
    };
    int*   deg  = (int*)alloc((size_t)N * 4);
    float* dinv = (float*)alloc((size_t)N * 4);
    int*   offs = (int*)alloc((size_t)(N + 1) * 4);
    int*   part = (int*)alloc((size_t)256 * 4);
    int*   bcnt = (int*)alloc((size_t)NB32 * 4);
    int*   csr  = (int*)alloc((size_t)E * 4);
    float* A    = (float*)alloc((size_t)N * 128 * 4);  // h1 / h3
    float* B    = (float*)alloc((size_t)N * 64 * 4);   // agg1/s2/s3/s4/s5
    float* C    = (float*)alloc((size_t)N * 64 * 4);   // h2/h4; aliased as tmp during build
    unsigned* tmp = (unsigned*)C;                      // E uint32 <= N*64*4 bytes

    hipMemsetAsync(deg, 0, (size_t)N * 4, stream);
    hipMemsetAsync(bcnt, 0, (size_t)NB32 * 4, stream);

    const int nb = (N + 2047) / 2048;

    k_count<<<(E + 255) / 256, 256, 0, stream>>>(dst, deg, E);
    k_dinv<<<(N + 255) / 256, 256, 0, stream>>>(deg, dinv, N);
    k_scan_part<<<nb, 256, 0, stream>>>(deg, part, N);
    k_scan_top<<<1, 256, 0, stream>>>(part, nb, offs, N);
    k_scan_emit<<<nb, 256, 0, stream>>>(deg, part, offs, N);
    k_fill_bin<<<(E + 255) / 256, 256, 0, stream>>>(src, dst, offs, bcnt, tmp, E);
    k_fill_csr<<<NB32, 256, 0, stream>>>(tmp, offs, csr, N);

    // Layer 1: agg1 = A.x (64 wide), then h1 = relu(agg1 @ W1 + b1) (128 wide)
    k_agg_l1<<<(N * 64 + 255) / 256, 256, 0, stream>>>(x, dinv, offs, csr, B, N);
    k_gemm<64, 128, 0><<<(N + 15) / 16, 256, 0, stream>>>(B, W1, b1, nullptr, A, N);
    // Layer 2
    k_gemm<128, 64, 1><<<(N + 31) / 32, 256, 0, stream>>>(A, W2, nullptr, dinv, B, N);
    k_agg<64, true><<<(N * 64 + 255) / 256, 256, 0, stream>>>(B, dinv, offs, csr, b2, C, N);
    // Layer 3
    k_gemm<64, 32, 1><<<(N + 63) / 64, 256, 0, stream>>>(C, W3, nullptr, dinv, B, N);
    k_agg<32, true><<<(N * 32 + 255) / 256, 256, 0, stream>>>(B, dinv, offs, csr, b3, A, N);
    // Layer 4
    k_gemm<32, 16, 1><<<(N + 127) / 128, 256, 0, stream>>>(A, W4, nullptr, dinv, B, N);
    k_agg<16, true><<<(N * 16 + 255) / 256, 256, 0, stream>>>(B, dinv, offs, csr, b4, C, N);
    // Layer 5
    k_gemm5<<<(N + 255) / 256, 256, 0, stream>>>(C, W5, dinv, B, N);
    k_agg<1, false><<<(N + 255) / 256, 256, 0, stream>>>(B, dinv, offs, csr, b5, (float*)d_out, N);
}

// Round 4
// 417.316 us; speedup vs baseline: 1.3901x; 1.3901x over previous
//
#include <hip/hip_runtime.h>
#include <math.h>

// GCN 5-layer: per layer relu(A @ (h @ W) + b), A = sym-normalized adj w/ self-loops.
// CSR-by-dst build, aggregate on the narrow side of each GEMM, fold dinv[src]
// row-scaling into GEMM epilogues. All fp32.
// R2: hierarchical scan (was 160us single-block).
// R3: binned fill — FAILED: 3125 machine-wide buckets still 80MB WRITE_SIZE
//     (lines written by many waves/XCDs over long windows -> evicted unfilled).
// R4: radix build, bins of 512 dsts: per-(block,bin) contiguous reservations in
//     k_binfill (single-wave line ownership), bin-local LDS degree/scan/csr in
//     k_csr. Replaces count/dinv/3-kernel-scan/2-pass-fill (205us) entirely.

#define NBIN_MAX 256
#define BSHIFT 9
#define BINW 512
#define CHUNK 8192

// Pass A: histogram of dst>>9 (sequential reads, LDS-local counts)
__global__ __launch_bounds__(256) void k_hist(const int* __restrict__ dst, int E,
                                              int nbin, int* __restrict__ binCnt) {
    __shared__ int h[NBIN_MAX];
    int t = threadIdx.x;
    for (int i = t; i < nbin; i += 256) h[i] = 0;
    __syncthreads();
    for (int e = blockIdx.x * 256 + t; e < E; e += gridDim.x * 256)
        atomicAdd(&h[dst[e] >> BSHIFT], 1);
    __syncthreads();
    for (int i = t; i < nbin; i += 256)
        if (h[i]) atomicAdd(&binCnt[i], h[i]);
}

// Pass A2: single-block exclusive scan of bin counts -> binBase[0..nbin], binCur
__global__ __launch_bounds__(256) void k_binscan(const int* __restrict__ binCnt,
                                                 int nbin, int* __restrict__ binBase,
                                                 int* __restrict__ binCur) {
    __shared__ int sh[256];
    int t = threadIdx.x;
    int v = (t < nbin) ? binCnt[t] : 0;
    sh[t] = v;
    __syncthreads();
    for (int d = 1; d < 256; d <<= 1) {
        int u = (t >= d) ? sh[t - d] : 0;
        __syncthreads();
        sh[t] += u;
        __syncthreads();
    }
    int ex = sh[t] - v;
    if (t < nbin) { binBase[t] = ex; binCur[t] = ex; }
    if (t == nbin - 1) binBase[nbin] = sh[t];  // = E
}

// Pass B: each block owns a contiguous CHUNK of edges; reserves per-bin space
// once, then writes contiguous runs. Payload: src<<9 | (dst&511).
__global__ __launch_bounds__(256) void k_binfill(const int* __restrict__ src,
                                                 const int* __restrict__ dst, int E,
                                                 int nbin, int* __restrict__ binCur,
                                                 unsigned* __restrict__ tmp) {
    __shared__ int h[NBIN_MAX];
    __shared__ int res[NBIN_MAX];
    int t = threadIdx.x;
    int e0 = blockIdx.x * CHUNK;
    int e1 = min(e0 + CHUNK, E);
    for (int i = t; i < nbin; i += 256) h[i] = 0;
    __syncthreads();
    for (int e = e0 + t; e < e1; e += 256)
        atomicAdd(&h[dst[e] >> BSHIFT], 1);
    __syncthreads();
    for (int i = t; i < nbin; i += 256)
        res[i] = h[i] ? atomicAdd(&binCur[i], h[i]) : 0;
    __syncthreads();
    for (int i = t; i < nbin; i += 256) h[i] = 0;
    __syncthreads();
    for (int e = e0 + t; e < e1; e += 256) {
        int d = dst[e];
        int b = d >> BSHIFT;
        int p = res[b] + atomicAdd(&h[b], 1);
        tmp[p] = ((unsigned)src[e] << BSHIFT) | (unsigned)(d & (BINW - 1));
    }
}

// Pass C: one block per bin. LDS degree count -> LDS scan -> emit dinv, offs,
// and final csr (single-block 32KB write window).
__global__ __launch_bounds__(256) void k_csr(const unsigned* __restrict__ tmp,
                                             const int* __restrict__ binBase,
                                             int n, int nbin,
                                             float* __restrict__ dinv,
                                             int* __restrict__ offs,
                                             int* __restrict__ csr) {
    __shared__ int ldeg[BINW];
    __shared__ int loff[BINW];
    __shared__ int pair[256];
    int b = blockIdx.x;
    int t = threadIdx.x;
    ldeg[t] = 0; ldeg[t + 256] = 0;
    __syncthreads();
    int lo = binBase[b], hi = binBase[b + 1];
    for (int p = lo + t; p < hi; p += 256)
        atomicAdd(&ldeg[tmp[p] & (BINW - 1u)], 1);
    __syncthreads();
    int a0 = ldeg[2 * t], a1 = ldeg[2 * t + 1];
    pair[t] = a0 + a1;
    __syncthreads();
    int v = pair[t];
    for (int d = 1; d < 256; d <<= 1) {
        int u = (t >= d) ? pair[t - d] : 0;
        __syncthreads();
        pair[t] += u;
        __syncthreads();
    }
    int ex = pair[t] - v;
    loff[2 * t] = ex;
    loff[2 * t + 1] = ex + a0;
    __syncthreads();
    int v0 = b << BSHIFT;
    for (int i = t; i < BINW; i += 256) {
        int vv = v0 + i;
        if (vv < n) {
            offs[vv] = lo + loff[i];
            dinv[vv] = 1.0f / sqrtf((float)(ldeg[i] + 1));
        }
    }
    if (t == 0 && b == nbin - 1) offs[n] = hi;
    __syncthreads();
    ldeg[t] = 0; ldeg[t + 256] = 0;  // reuse as cursors
    __syncthreads();
    for (int p = lo + t; p < hi; p += 256) {
        unsigned u = tmp[p];
        int d0 = (int)(u & (BINW - 1u));
        int pos = loff[d0] + atomicAdd(&ldeg[d0], 1);
        csr[lo + pos] = (int)(u >> BSHIFT);
    }
}

// Layer-1 aggregation straight from x: out[v] = dinv[v]*(sum_u x[u]*dinv[u] + x[v]*dinv[v])
__global__ __launch_bounds__(256) void k_agg_l1(const float* __restrict__ X,
                                                const float* __restrict__ dinv,
                                                const int* __restrict__ offs,
                                                const int* __restrict__ csr,
                                                float* __restrict__ Y, int n) {
    constexpr int W = 64;
    int t = blockIdx.x * 256 + threadIdx.x;
    int v = t / W, c = t % W;
    if (v >= n) return;
    float dv = dinv[v];
    float sum = X[(size_t)v * W + c] * dv;
    int e = offs[v], re = offs[v + 1];
    for (; e + 4 <= re; e += 4) {
        int u0 = csr[e], u1 = csr[e + 1], u2 = csr[e + 2], u3 = csr[e + 3];
        float a0 = X[(size_t)u0 * W + c] * dinv[u0];
        float a1 = X[(size_t)u1 * W + c] * dinv[u1];
        float a2 = X[(size_t)u2 * W + c] * dinv[u2];
        float a3 = X[(size_t)u3 * W + c] * dinv[u3];
        sum += a0 + a1 + a2 + a3;
    }
    for (; e < re; ++e) { int u = csr[e]; sum += X[(size_t)u * W + c] * dinv[u]; }
    Y[(size_t)v * W + c] = dv * sum;
}

// Generic aggregation over pre-scaled rows S: out[v] = act(dinv[v]*(sum_u S[u] + S[v]) + b)
template <int W, bool RELU>
__global__ __launch_bounds__(256) void k_agg(const float* __restrict__ S,
                                             const float* __restrict__ dinv,
                                             const int* __restrict__ offs,
                                             const int* __restrict__ csr,
                                             const float* __restrict__ bg,
                                             float* __restrict__ Y, int n) {
    int t = blockIdx.x * 256 + threadIdx.x;
    int v = t / W, c = t % W;
    if (v >= n) return;
    float sum = S[(size_t)v * W + c];
    int e = offs[v], re = offs[v + 1];
    for (; e + 4 <= re; e += 4) {
        int u0 = csr[e], u1 = csr[e + 1], u2 = csr[e + 2], u3 = csr[e + 3];
        float a0 = S[(size_t)u0 * W + c];
        float a1 = S[(size_t)u1 * W + c];
        float a2 = S[(size_t)u2 * W + c];
        float a3 = S[(size_t)u3 * W + c];
        sum += a0 + a1 + a2 + a3;
    }
    for (; e < re; ++e) sum += S[(size_t)csr[e] * W + c];
    float r = dinv[v] * sum + bg[c];
    if (RELU) r = fmaxf(r, 0.0f);
    Y[(size_t)v * W + c] = r;
}

// Tall-skinny GEMM: Y[n,OUT] = X[n,IN] @ Wg[IN,OUT]
//   EPI==0: += bias, relu    EPI==1: *= dinv[row]
template <int IN, int OUT, int EPI>
__global__ __launch_bounds__(256) void k_gemm(const float* __restrict__ X,
                                              const float* __restrict__ Wg,
                                              const float* __restrict__ bg,
                                              const float* __restrict__ dinv,
                                              float* __restrict__ Y, int nrows) {
    constexpr int TPR = OUT / 4;
    constexpr int GROUPS = 256 / TPR;
    constexpr int ROWS = GROUPS * 2;
    __shared__ __align__(16) float Wl[IN * OUT];
    __shared__ __align__(16) float xl[ROWS * IN];
    __shared__ float bl[OUT];
    int tid = threadIdx.x;
    for (int i = tid; i < IN * OUT; i += 256) Wl[i] = Wg[i];
    if (EPI == 0)
        for (int i = tid; i < OUT; i += 256) bl[i] = bg[i];
    int base = blockIdx.x * ROWS;
    for (int i = tid; i < ROWS * IN; i += 256) {
        int r = base + i / IN;
        xl[i] = (r < nrows) ? X[(size_t)base * IN + i] : 0.0f;
    }
    __syncthreads();
    int g = tid / TPR;
    int c0 = (tid % TPR) * 4;
    int r0 = base + g * 2, r1 = r0 + 1;
    int l0 = (g * 2) * IN, l1 = l0 + IN;
    float4 acc0 = make_float4(0.f, 0.f, 0.f, 0.f);
    float4 acc1 = make_float4(0.f, 0.f, 0.f, 0.f);
#pragma unroll 8
    for (int k = 0; k < IN; ++k) {
        float4 w = *(const float4*)&Wl[k * OUT + c0];
        float a0 = xl[l0 + k], a1 = xl[l1 + k];
        acc0.x += a0 * w.x; acc0.y += a0 * w.y; acc0.z += a0 * w.z; acc0.w += a0 * w.w;
        acc1.x += a1 * w.x; acc1.y += a1 * w.y; acc1.z += a1 * w.z; acc1.w += a1 * w.w;
    }
    if (EPI == 0) {
        float bx = bl[c0], by = bl[c0 + 1], bz = bl[c0 + 2], bw = bl[c0 + 3];
        acc0.x = fmaxf(acc0.x + bx, 0.f); acc0.y = fmaxf(acc0.y + by, 0.f);
        acc0.z = fmaxf(acc0.z + bz, 0.f); acc0.w = fmaxf(acc0.w + bw, 0.f);
        acc1.x = fmaxf(acc1.x + bx, 0.f); acc1.y = fmaxf(acc1.y + by, 0.f);
        acc1.z = fmaxf(acc1.z + bz, 0.f); acc1.w = fmaxf(acc1.w + bw, 0.f);
    } else {
        if (r0 < nrows) { float d0 = dinv[r0]; acc0.x *= d0; acc0.y *= d0; acc0.z *= d0; acc0.w *= d0; }
        if (r1 < nrows) { float d1 = dinv[r1]; acc1.x *= d1; acc1.y *= d1; acc1.z *= d1; acc1.w *= d1; }
    }
    if (r0 < nrows) *(float4*)&Y[(size_t)r0 * OUT + c0] = acc0;
    if (r1 < nrows) *(float4*)&Y[(size_t)r1 * OUT + c0] = acc1;
}

__global__ __launch_bounds__(256) void k_gemm5(const float* __restrict__ X,
                                               const float* __restrict__ Wg,
                                               const float* __restrict__ dinv,
                                               float* __restrict__ Y, int n) {
    int r = blockIdx.x * 256 + threadIdx.x;
    if (r >= n) return;
    float acc = 0.f;
#pragma unroll
    for (int k = 0; k < 16; ++k) acc += X[(size_t)r * 16 + k] * Wg[k];
    Y[r] = acc * dinv[r];
}

extern "C" void kernel_launch(void* const* d_in, const int* in_sizes, int n_in,
                              void* d_out, int out_size, void* d_ws, size_t ws_size,
                              hipStream_t stream) {
    const float* x  = (const float*)d_in[0];
    const int*   ei = (const int*)d_in[1];
    const float* W1 = (const float*)d_in[2];  const float* b1 = (const float*)d_in[3];
    const float* W2 = (const float*)d_in[4];  const float* b2 = (const float*)d_in[5];
    const float* W3 = (const float*)d_in[6];  const float* b3 = (const float*)d_in[7];
    const float* W4 = (const float*)d_in[8];  const float* b4 = (const float*)d_in[9];
    const float* W5 = (const float*)d_in[10]; const float* b5 = (const float*)d_in[11];

    const int N = in_sizes[0] / 64;   // 100000
    const int E = in_sizes[1] / 2;    // 1600000
    const int* src = ei;
    const int* dst = ei + E;
    const int nbin = (N + BINW - 1) / BINW;   // 196

    char* ws = (char*)d_ws;
    size_t off = 0;
    auto alloc = [&](size_t bytes) -> void* {
        void* p = ws + off;
        off = (off + bytes + 255) & ~(size_t)255;
        return p;
    };
    float* dinv    = (float*)alloc((size_t)N * 4);
    int*   offs    = (int*)alloc((size_t)(N + 1) * 4);
    int*   binCnt  = (int*)alloc((size_t)NBIN_MAX * 4);
    int*   binBase = (int*)alloc((size_t)(NBIN_MAX + 1) * 4);
    int*   binCur  = (int*)alloc((size_t)NBIN_MAX * 4);
    int*   csr     = (int*)alloc((size_t)E * 4);
    float* A       = (float*)alloc((size_t)N * 128 * 4);  // h1 / h3
    float* B       = (float*)alloc((size_t)N * 64 * 4);   // agg1/s2/s3/s4/s5
    float* C       = (float*)alloc((size_t)N * 64 * 4);   // h2/h4; aliased as tmp
    unsigned* tmp  = (unsigned*)C;                        // E u32 <= N*64*4 bytes

    hipMemsetAsync(binCnt, 0, (size_t)NBIN_MAX * 4, stream);

    k_hist<<<256, 256, 0, stream>>>(dst, E, nbin, binCnt);
    k_binscan<<<1, 256, 0, stream>>>(binCnt, nbin, binBase, binCur);
    k_binfill<<<(E + CHUNK - 1) / CHUNK, 256, 0, stream>>>(src, dst, E, nbin, binCur, tmp);
    k_csr<<<nbin, 256, 0, stream>>>(tmp, binBase, N, nbin, dinv, offs, csr);

    // Layer 1: agg1 = A.x (64 wide), then h1 = relu(agg1 @ W1 + b1) (128 wide)
    k_agg_l1<<<(N * 64 + 255) / 256, 256, 0, stream>>>(x, dinv, offs, csr, B, N);
    k_gemm<64, 128, 0><<<(N + 15) / 16, 256, 0, stream>>>(B, W1, b1, nullptr, A, N);
    // Layer 2
    k_gemm<128, 64, 1><<<(N + 31) / 32, 256, 0, stream>>>(A, W2, nullptr, dinv, B, N);
    k_agg<64, true><<<(N * 64 + 255) / 256, 256, 0, stream>>>(B, dinv, offs, csr, b2, C, N);
    // Layer 3
    k_gemm<64, 32, 1><<<(N + 63) / 64, 256, 0, stream>>>(C, W3, nullptr, dinv, B, N);
    k_agg<32, true><<<(N * 32 + 255) / 256, 256, 0, stream>>>(B, dinv, offs, csr, b3, A, N);
    // Layer 4
    k_gemm<32, 16, 1><<<(N + 127) / 128, 256, 0, stream>>>(A, W4, nullptr, dinv, B, N);
    k_agg<16, true><<<(N * 16 + 255) / 256, 256, 0, stream>>>(B, dinv, offs, csr, b4, C, N);
    // Layer 5
    k_gemm5<<<(N + 255) / 256, 256, 0, stream>>>(C, W5, dinv, B, N);
    k_agg<1, false><<<(N + 255) / 256, 256, 0, stream>>>(B, dinv, offs, csr, b5, (float*)d_out, N);
}